// Round 2
// baseline (82.796 us; speedup 1.0000x reference)
//
#include <hip/hip_runtime.h>

// StateSpaceLayer: out[b,t,r,c] = sum_{j<=t} A[r]^(t-j) * x[b,j,r,c]
// == linear recurrence state[t] = A[r]*state[t-1] + x[t] along seq.
// Shapes: x (4,512,64,64) f32, A (64,) f32, out same as x. Memory-bound:
// 67 MB total -> ~10.6 us roofline at 6.3 TB/s.
//
// Layout: block = (bi, r) -> 256 blocks (1/CU). Thread = (w=seq-chunk, q=c/4).
// float4 along c: 16 B/lane, 1 KB per wave mem-instruction. 256 thr/block
// with __launch_bounds__(256,1) -> VGPR cap 512 so local[32] float4 (128
// VGPRs) + clustered loads stay in registers (the previous 1024-thr version
// was capped at 128 VGPRs -> load flight starved -> 0.8 TB/s).

#define B_     4
#define SEQ_   512
#define D_     64
#define CHUNK_ 32
#define NCHUNK_ (SEQ_ / CHUNK_)   // 16 chunks
#define Q_      (D_ / 4)          // 16 float4 per (j,r) row

__global__ __launch_bounds__(NCHUNK_ * Q_, 1) void ssm_scan_kernel(
    const float4* __restrict__ x, const float* __restrict__ A,
    float4* __restrict__ out)
{
    __shared__ float4 Elds[NCHUNK_][Q_];   // chunk-end states (4 KB)

    const int bi  = blockIdx.x >> 6;       // batch
    const int r   = blockIdx.x & 63;       // decay row (block-uniform)
    const int tid = threadIdx.x;
    const int w   = tid >> 4;              // chunk id 0..15
    const int q   = tid & 15;              // float4 column 0..15

    const float a = fmaxf(A[r], 1e-6f);    // block-uniform -> SGPR

    const int j0 = w * CHUNK_;
    // float4 index of x[bi, j, r, 4q] = ((bi*SEQ + j)*D + r)*Q + q
    const size_t  base    = ((size_t)(bi * SEQ_ + j0) * D_ + r) * Q_ + q;
    const float4* xp      = x + base;
    float4*       op      = out + base;
    const int     jstride = D_ * Q_;       // 1024 float4 between timesteps

    // Phase 1: local scan of this chunk, zero initial state; keep prefix
    // values in registers (128 VGPRs).
    float4 local[CHUNK_];
    float4 s = make_float4(0.f, 0.f, 0.f, 0.f);
    #pragma unroll
    for (int t = 0; t < CHUNK_; ++t) {
        float4 v = xp[(size_t)t * jstride];
        s.x = fmaf(s.x, a, v.x);
        s.y = fmaf(s.y, a, v.y);
        s.z = fmaf(s.z, a, v.z);
        s.w = fmaf(s.w, a, v.w);
        local[t] = s;
    }

    Elds[w][q] = s;
    __syncthreads();

    // a^CHUNK_ via 5 squarings (scalar).
    float aL = a * a;   // a^2
    aL = aL * aL;       // a^4
    aL = aL * aL;       // a^8
    aL = aL * aL;       // a^16
    aL = aL * aL;       // a^32

    // Carry into this chunk: Horner over lower chunks' end states.
    float4 carry = make_float4(0.f, 0.f, 0.f, 0.f);
    for (int wp = 0; wp < w; ++wp) {
        float4 e = Elds[wp][q];
        carry.x = fmaf(carry.x, aL, e.x);
        carry.y = fmaf(carry.y, aL, e.y);
        carry.z = fmaf(carry.z, aL, e.z);
        carry.w = fmaf(carry.w, aL, e.w);
    }

    // Phase 3: out[j0+t] = local[t] + carry * a^(t+1), store float4.
    float p = a;
    #pragma unroll
    for (int t = 0; t < CHUNK_; ++t) {
        float4 o;
        o.x = fmaf(carry.x, p, local[t].x);
        o.y = fmaf(carry.y, p, local[t].y);
        o.z = fmaf(carry.z, p, local[t].z);
        o.w = fmaf(carry.w, p, local[t].w);
        op[(size_t)t * jstride] = o;
        p *= a;
    }
}

extern "C" void kernel_launch(void* const* d_in, const int* in_sizes, int n_in,
                              void* d_out, int out_size, void* d_ws, size_t ws_size,
                              hipStream_t stream) {
    const float4* x   = (const float4*)d_in[0];
    const float*  A   = (const float*)d_in[1];
    float4*       out = (float4*)d_out;

    dim3 grid(B_ * D_);              // 256 blocks, one per (batch, r)
    dim3 block(NCHUNK_ * Q_);        // 256 threads = 4 waves
    hipLaunchKernelGGL(ssm_scan_kernel, grid, block, 0, stream, x, A, out);
}